// Round 1
// baseline (1399.500 us; speedup 1.0000x reference)
//
#include <hip/hip_runtime.h>
#include <stdint.h>

#define NB 4
#define LL 4096
#define DD 2048
#define HH 8192
#define CAP 2048
#define BLD (NB * LL * DD)

typedef __attribute__((ext_vector_type(8))) short bf16x8;
typedef __attribute__((ext_vector_type(4))) float f32x4;
typedef __attribute__((ext_vector_type(8))) unsigned short u16x8;

__device__ __forceinline__ ushort f2b(float f) {
  union { float f; uint32_t u; } c; c.f = f;
  uint32_t u = c.u;
  return (ushort)((u + 0x7FFFu + ((u >> 16) & 1u)) >> 16);
}
__device__ __forceinline__ float b2f(ushort h) {
  union { uint32_t u; float f; } c; c.u = ((uint32_t)h) << 16;
  return c.f;
}

// ---------------- init: zero the small accumulators --------------------------
__global__ void init_kernel(float* probsum, int* cnts) {
  int t = threadIdx.x;
  if (t < NB) probsum[t] = 0.f;
  if (t < 2 * NB) cnts[t] = 0;
}

// ---------------- router: logits -> keys, probs, per-batch prob sums ---------
__global__ void __launch_bounds__(256) router_kernel(
    const float* __restrict__ x, const float* __restrict__ wr,
    uint32_t* __restrict__ keys, float* __restrict__ probs,
    float* __restrict__ probsum) {
  int tok = blockIdx.x;  // 0..16383
  int t = threadIdx.x;
  const float4* xr = (const float4*)(x + (size_t)tok * DD);
  const float4* wv = (const float4*)wr;
  float4 a0 = xr[2 * t], a1 = xr[2 * t + 1];
  float4 w0 = wv[2 * t], w1 = wv[2 * t + 1];
  float s = a0.x * w0.x + a0.y * w0.y + a0.z * w0.z + a0.w * w0.w +
            a1.x * w1.x + a1.y * w1.y + a1.z * w1.z + a1.w * w1.w;
  for (int o = 32; o; o >>= 1) s += __shfl_down(s, o, 64);
  __shared__ float red[4];
  int wave = t >> 6, lane = t & 63;
  if (lane == 0) red[wave] = s;
  __syncthreads();
  if (t == 0) {
    float logit = red[0] + red[1] + red[2] + red[3];
    float p = 1.f / (1.f + __expf(-logit));
    probs[tok] = p;
    union { float f; uint32_t u; } c; c.f = logit;
    uint32_t u = c.u;
    keys[tok] = (u & 0x80000000u) ? ~u : (u | 0x80000000u);
    atomicAdd(&probsum[tok >> 12], p);  // L = 4096 = 2^12
  }
}

// ---------------- per-batch k-th largest via 32-bit radix bisection ----------
__global__ void __launch_bounds__(256) thresh_kernel(
    const uint32_t* __restrict__ keys, uint32_t* __restrict__ Vout,
    int* __restrict__ cgt) {
  int b = blockIdx.x;
  __shared__ uint32_t k_[LL];
  __shared__ int red[4];
  int t = threadIdx.x;
  for (int i = t; i < LL; i += 256) k_[i] = keys[b * LL + i];
  __syncthreads();
  uint32_t cur = 0;
  for (int bit = 31; bit >= 0; --bit) {
    uint32_t cand = cur | (1u << bit);
    int c = 0;
    for (int i = t; i < LL; i += 256) c += (k_[i] >= cand) ? 1 : 0;
    for (int o = 32; o; o >>= 1) c += __shfl_down(c, o, 64);
    if ((t & 63) == 0) red[t >> 6] = c;
    __syncthreads();
    int tot = red[0] + red[1] + red[2] + red[3];
    if (tot >= CAP) cur = cand;  // uniform across block
    __syncthreads();
  }
  // count strictly greater than V
  int c = 0;
  for (int i = t; i < LL; i += 256) c += (k_[i] > cur) ? 1 : 0;
  for (int o = 32; o; o >>= 1) c += __shfl_down(c, o, 64);
  if ((t & 63) == 0) red[t >> 6] = c;
  __syncthreads();
  if (t == 0) {
    Vout[b] = cur;
    cgt[b] = red[0] + red[1] + red[2] + red[3];
  }
}

// ---------------- compact selected indices (order irrelevant for scatter) ----
__global__ void __launch_bounds__(256) select_kernel(
    const uint32_t* __restrict__ keys, const uint32_t* __restrict__ V,
    const int* __restrict__ cgt, int* __restrict__ cnts,
    int* __restrict__ sel_idx, int* __restrict__ tok2slot) {
  int i = blockIdx.x * 256 + threadIdx.x;  // 0..16383
  int b = i >> 12, l = i & (LL - 1);
  uint32_t k = keys[i], v = V[b];
  int slot = -1;
  if (k > v) {
    slot = atomicAdd(&cnts[b], 1);             // < cgt[b] < CAP
  } else if (k == v) {
    int e = atomicAdd(&cnts[NB + b], 1);       // fill from the back
    int s = CAP - 1 - e;
    if (s >= cgt[b]) slot = s;
  }
  tok2slot[i] = slot;
  if (slot >= 0) sel_idx[b * CAP + slot] = l;
}

// ---------------- gather selected rows, f32 -> bf16 --------------------------
__global__ void __launch_bounds__(256) gather_kernel(
    const float* __restrict__ x, const int* __restrict__ sel_idx,
    ushort* __restrict__ xsel) {
  int r = blockIdx.x;  // 0..8191
  int b = r >> 11, s = r & (CAP - 1);
  int l = sel_idx[b * CAP + s];
  int t = threadIdx.x;
  const float4* src = (const float4*)(x + ((size_t)(b * LL + l)) * DD);
  float4 a0 = src[2 * t], a1 = src[2 * t + 1];
  u16x8 o;
  o[0] = f2b(a0.x); o[1] = f2b(a0.y); o[2] = f2b(a0.z); o[3] = f2b(a0.w);
  o[4] = f2b(a1.x); o[5] = f2b(a1.y); o[6] = f2b(a1.z); o[7] = f2b(a1.w);
  ((u16x8*)(xsel + (size_t)r * DD))[t] = o;
}

// ---------------- transpose f32 [R][C] -> bf16 [C][R] ------------------------
__global__ void transpose_kernel(const float* __restrict__ in,
                                 ushort* __restrict__ out, int R, int C) {
  __shared__ float tile[32][33];
  int c0 = blockIdx.x * 32, r0 = blockIdx.y * 32;
  int tx = threadIdx.x, ty = threadIdx.y;  // (32,8)
#pragma unroll
  for (int i = 0; i < 4; i++)
    tile[ty + i * 8][tx] = in[(size_t)(r0 + ty + i * 8) * C + c0 + tx];
  __syncthreads();
#pragma unroll
  for (int i = 0; i < 4; i++)
    out[(size_t)(c0 + ty + i * 8) * R + r0 + tx] = f2b(tile[tx][ty + i * 8]);
}

// ---------------- m97-style 128x128 bf16 GEMM core (A[M][K] x BT[N][K]) ------
__device__ __forceinline__ void gemm_core(const ushort* __restrict__ A,
                                          const ushort* __restrict__ BT,
                                          int K, int rowA0, int colB0,
                                          ushort* As, ushort* Bs,
                                          f32x4 acc[4][4]) {
  int t = threadIdx.x;
  int wave = t >> 6, lane = t & 63;
  int wr = wave >> 1, wc = wave & 1;
  int lrow = lane & 15;
  int lk = (lane >> 4) << 3;  // 0/8/16/24
  int r0 = t >> 2;            // staging row 0..63
  int c0 = (t & 3) << 3;      // staging col (bf16 elems)
  const ushort* Ag = A + (size_t)(rowA0 + r0) * K + c0;
  const ushort* Ag2 = Ag + (size_t)64 * K;
  const ushort* Bg = BT + (size_t)(colB0 + r0) * K + c0;
  const ushort* Bg2 = Bg + (size_t)64 * K;
  char* AsB = (char*)As;
  char* BsB = (char*)Bs;
  for (int kt = 0; kt < K; kt += 32) {
    __builtin_amdgcn_global_load_lds(
        (const __attribute__((address_space(1))) void*)(Ag + kt),
        (__attribute__((address_space(3))) void*)(AsB + wave * 1024), 16, 0, 0);
    __builtin_amdgcn_global_load_lds(
        (const __attribute__((address_space(1))) void*)(Ag2 + kt),
        (__attribute__((address_space(3))) void*)(AsB + 4096 + wave * 1024), 16, 0, 0);
    __builtin_amdgcn_global_load_lds(
        (const __attribute__((address_space(1))) void*)(Bg + kt),
        (__attribute__((address_space(3))) void*)(BsB + wave * 1024), 16, 0, 0);
    __builtin_amdgcn_global_load_lds(
        (const __attribute__((address_space(1))) void*)(Bg2 + kt),
        (__attribute__((address_space(3))) void*)(BsB + 4096 + wave * 1024), 16, 0, 0);
    __syncthreads();
    bf16x8 aF[4], bF[4];
    const ushort* Asr = As + (wr * 64 + lrow) * 32 + lk;
    const ushort* Bsr = Bs + (wc * 64 + lrow) * 32 + lk;
#pragma unroll
    for (int m = 0; m < 4; m++) aF[m] = *(const bf16x8*)(Asr + m * 16 * 32);
#pragma unroll
    for (int n = 0; n < 4; n++) bF[n] = *(const bf16x8*)(Bsr + n * 16 * 32);
#pragma unroll
    for (int m = 0; m < 4; m++)
#pragma unroll
      for (int n = 0; n < 4; n++)
        acc[m][n] = __builtin_amdgcn_mfma_f32_16x16x32_bf16(aF[m], bF[n],
                                                            acc[m][n], 0, 0, 0);
    __syncthreads();
  }
}

// ---------------- GEMM1: h = gelu_tanh(xsel @ W1 + b1), bf16 out -------------
__global__ void __launch_bounds__(256) gemm1_kernel(
    const ushort* __restrict__ A, const ushort* __restrict__ BT,
    const float* __restrict__ b1, ushort* __restrict__ hOut) {
  __shared__ ushort As[128 * 32], Bs[128 * 32];
  f32x4 acc[4][4];
#pragma unroll
  for (int m = 0; m < 4; m++)
#pragma unroll
    for (int n = 0; n < 4; n++) acc[m][n] = (f32x4){0.f, 0.f, 0.f, 0.f};
  int tm = blockIdx.y * 128, tn = blockIdx.x * 128;
  gemm_core(A, BT, DD, tm, tn, As, Bs, acc);
  int t = threadIdx.x, wave = t >> 6, lane = t & 63;
  int wr = wave >> 1, wc = wave & 1;
  int colBase = tn + wc * 64 + (lane & 15);
  int rowBase = tm + wr * 64 + ((lane >> 4) << 2);
#pragma unroll
  for (int m = 0; m < 4; m++)
#pragma unroll
    for (int n = 0; n < 4; n++) {
      int col = colBase + n * 16;
      float bias = b1[col];
#pragma unroll
      for (int r = 0; r < 4; r++) {
        int row = rowBase + m * 16 + r;
        float v = acc[m][n][r] + bias;
        // gelu_tanh(v) = v * sigmoid(1.5957691216*(v + 0.044715 v^3))
        float u = 1.5957691216057308f * (v + 0.044715f * v * v * v);
        float g = v / (1.f + __expf(-u));
        hOut[(size_t)row * HH + col] = f2b(g);
      }
    }
}

// ---------------- GEMM2: out_sel = h @ W2 + b2, bf16 out ---------------------
__global__ void __launch_bounds__(256) gemm2_kernel(
    const ushort* __restrict__ A, const ushort* __restrict__ BT,
    const float* __restrict__ b2, ushort* __restrict__ out_sel) {
  __shared__ ushort As[128 * 32], Bs[128 * 32];
  f32x4 acc[4][4];
#pragma unroll
  for (int m = 0; m < 4; m++)
#pragma unroll
    for (int n = 0; n < 4; n++) acc[m][n] = (f32x4){0.f, 0.f, 0.f, 0.f};
  int tm = blockIdx.y * 128, tn = blockIdx.x * 128;
  gemm_core(A, BT, HH, tm, tn, As, Bs, acc);
  int t = threadIdx.x, wave = t >> 6, lane = t & 63;
  int wr = wave >> 1, wc = wave & 1;
  int colBase = tn + wc * 64 + (lane & 15);
  int rowBase = tm + wr * 64 + ((lane >> 4) << 2);
#pragma unroll
  for (int m = 0; m < 4; m++)
#pragma unroll
    for (int n = 0; n < 4; n++) {
      int col = colBase + n * 16;
      float bias = b2[col];
#pragma unroll
      for (int r = 0; r < 4; r++) {
        int row = rowBase + m * 16 + r;
        out_sel[(size_t)row * DD + col] = f2b(acc[m][n][r] + bias);
      }
    }
}

// ---------------- final: out = x (unselected) | blend (selected) -------------
__global__ void __launch_bounds__(256) final_kernel(
    const float* __restrict__ x, const float* __restrict__ probs,
    const int* __restrict__ tok2slot, const ushort* __restrict__ out_sel,
    float* __restrict__ outF) {
  int tok = blockIdx.x;
  int b = tok >> 12;
  int slot = tok2slot[tok];
  float p = probs[tok];
  int t = threadIdx.x;
  const float4* xr = (const float4*)(x + (size_t)tok * DD);
  float4* od = (float4*)(outF + (size_t)tok * DD);
  float4 a0 = xr[2 * t], a1 = xr[2 * t + 1];
  if (slot >= 0) {
    u16x8 q = ((const u16x8*)(out_sel + ((size_t)((b << 11) + slot)) * DD))[t];
    float q1p = 1.f - p;
    a0.x = p * b2f(q[0]) + q1p * a0.x;
    a0.y = p * b2f(q[1]) + q1p * a0.y;
    a0.z = p * b2f(q[2]) + q1p * a0.z;
    a0.w = p * b2f(q[3]) + q1p * a0.w;
    a1.x = p * b2f(q[4]) + q1p * a1.x;
    a1.y = p * b2f(q[5]) + q1p * a1.y;
    a1.z = p * b2f(q[6]) + q1p * a1.z;
    a1.w = p * b2f(q[7]) + q1p * a1.w;
  }
  od[2 * t] = a0;
  od[2 * t + 1] = a1;
}

// ---------------- aux loss ---------------------------------------------------
__global__ void aux_kernel(const float* __restrict__ probsum,
                           float* __restrict__ outaux) {
  if (threadIdx.x == 0) {
    float s = 0.f;
#pragma unroll
    for (int b = 0; b < NB; b++) {
      float m = probsum[b] * (1.f / (float)LL) - 0.5f;
      s += m * m;
    }
    outaux[0] = 0.01f * s * (1.f / (float)NB);
  }
}

// ---------------- launch -----------------------------------------------------
extern "C" void kernel_launch(void* const* d_in, const int* in_sizes, int n_in,
                              void* d_out, int out_size, void* d_ws,
                              size_t ws_size, hipStream_t stream) {
  const float* x = (const float*)d_in[0];
  const float* w_router = (const float*)d_in[1];
  const float* W1 = (const float*)d_in[2];  // [D][H]
  const float* b1 = (const float*)d_in[3];
  const float* W2 = (const float*)d_in[4];  // [H][D]
  const float* b2 = (const float*)d_in[5];
  float* outF = (float*)d_out;

  char* w = (char*)d_ws;
  uint32_t* keys   = (uint32_t*)(w);                 // 64 KB
  float*    probs  = (float*)(w + 65536);            // 64 KB
  float*    probsum= (float*)(w + 131072);           // 256 B
  int*      cnts   = (int*)(w + 131328);             // 256 B
  uint32_t* V      = (uint32_t*)(w + 131584);        // 256 B
  int*      cgt    = (int*)(w + 131840);             // 256 B
  int*      sel_idx= (int*)(w + 132096);             // 32 KB
  int*      tok2slot=(int*)(w + 164864);             // 64 KB
  ushort*   xsel   = (ushort*)(w + 230400);          // 32 MB  [8192][2048]
  ushort*   W1T    = (ushort*)(w + 230400 + 33554432);       // [H][D]
  ushort*   W2T    = (ushort*)(w + 230400 + 2 * 33554432);   // [D][H]
  ushort*   out_sel= (ushort*)(w + 230400 + (size_t)3 * 33554432);  // [8192][2048]

  ushort* hbuf = (ushort*)d_out;  // h [8192][8192] bf16 scratch, overwritten later

  init_kernel<<<1, 64, 0, stream>>>(probsum, cnts);
  router_kernel<<<NB * LL, 256, 0, stream>>>(x, w_router, keys, probs, probsum);
  thresh_kernel<<<NB, 256, 0, stream>>>(keys, V, cgt);
  select_kernel<<<NB * LL / 256, 256, 0, stream>>>(keys, V, cgt, cnts, sel_idx,
                                                   tok2slot);
  gather_kernel<<<NB * CAP, 256, 0, stream>>>(x, sel_idx, xsel);
  transpose_kernel<<<dim3(HH / 32, DD / 32), dim3(32, 8), 0, stream>>>(W1, W1T,
                                                                       DD, HH);
  transpose_kernel<<<dim3(DD / 32, HH / 32), dim3(32, 8), 0, stream>>>(W2, W2T,
                                                                       HH, DD);
  gemm1_kernel<<<dim3(HH / 128, NB * CAP / 128), 256, 0, stream>>>(xsel, W1T,
                                                                   b1, hbuf);
  gemm2_kernel<<<dim3(DD / 128, NB * CAP / 128), 256, 0, stream>>>(hbuf, W2T,
                                                                   b2, out_sel);
  final_kernel<<<NB * LL, 256, 0, stream>>>(x, probs, tok2slot, out_sel, outF);
  aux_kernel<<<1, 64, 0, stream>>>(probsum, outF + BLD);
}

// Round 3
// 1176.569 us; speedup vs baseline: 1.1895x; 1.1895x over previous
//
#include <hip/hip_runtime.h>
#include <stdint.h>

#define NB 4
#define LL 4096
#define DD 2048
#define HH 8192
#define CAP 2048
#define BLD (NB * LL * DD)

typedef __attribute__((ext_vector_type(8))) short bf16x8;
typedef __attribute__((ext_vector_type(4))) float f32x4;
typedef __attribute__((ext_vector_type(8))) unsigned short u16x8;

__device__ __forceinline__ ushort f2b(float f) {
  union { float f; uint32_t u; } c; c.f = f;
  uint32_t u = c.u;
  return (ushort)((u + 0x7FFFu + ((u >> 16) & 1u)) >> 16);
}
__device__ __forceinline__ float b2f(ushort h) {
  union { uint32_t u; float f; } c; c.u = ((uint32_t)h) << 16;
  return c.f;
}

// ---------------- init: zero the small accumulators --------------------------
__global__ void init_kernel(float* probsum, int* cnts) {
  int t = threadIdx.x;
  if (t < NB) probsum[t] = 0.f;
  if (t < 2 * NB) cnts[t] = 0;
}

// ---------------- router: logits -> keys, probs, per-batch prob sums ---------
__global__ void __launch_bounds__(256) router_kernel(
    const float* __restrict__ x, const float* __restrict__ wr,
    uint32_t* __restrict__ keys, float* __restrict__ probs,
    float* __restrict__ probsum) {
  int tok = blockIdx.x;  // 0..16383
  int t = threadIdx.x;
  const float4* xr = (const float4*)(x + (size_t)tok * DD);
  const float4* wv = (const float4*)wr;
  float4 a0 = xr[2 * t], a1 = xr[2 * t + 1];
  float4 w0 = wv[2 * t], w1 = wv[2 * t + 1];
  float s = a0.x * w0.x + a0.y * w0.y + a0.z * w0.z + a0.w * w0.w +
            a1.x * w1.x + a1.y * w1.y + a1.z * w1.z + a1.w * w1.w;
  for (int o = 32; o; o >>= 1) s += __shfl_down(s, o, 64);
  __shared__ float red[4];
  int wave = t >> 6, lane = t & 63;
  if (lane == 0) red[wave] = s;
  __syncthreads();
  if (t == 0) {
    float logit = red[0] + red[1] + red[2] + red[3];
    float p = 1.f / (1.f + __expf(-logit));
    probs[tok] = p;
    union { float f; uint32_t u; } c; c.f = logit;
    uint32_t u = c.u;
    keys[tok] = (u & 0x80000000u) ? ~u : (u | 0x80000000u);
    atomicAdd(&probsum[tok >> 12], p);  // L = 4096 = 2^12
  }
}

// ---------------- per-batch k-th largest via 32-bit radix bisection ----------
__global__ void __launch_bounds__(256) thresh_kernel(
    const uint32_t* __restrict__ keys, uint32_t* __restrict__ Vout,
    int* __restrict__ cgt) {
  int b = blockIdx.x;
  __shared__ uint32_t k_[LL];
  __shared__ int red[4];
  int t = threadIdx.x;
  for (int i = t; i < LL; i += 256) k_[i] = keys[b * LL + i];
  __syncthreads();
  uint32_t cur = 0;
  for (int bit = 31; bit >= 0; --bit) {
    uint32_t cand = cur | (1u << bit);
    int c = 0;
    for (int i = t; i < LL; i += 256) c += (k_[i] >= cand) ? 1 : 0;
    for (int o = 32; o; o >>= 1) c += __shfl_down(c, o, 64);
    if ((t & 63) == 0) red[t >> 6] = c;
    __syncthreads();
    int tot = red[0] + red[1] + red[2] + red[3];
    if (tot >= CAP) cur = cand;  // uniform across block
    __syncthreads();
  }
  int c = 0;
  for (int i = t; i < LL; i += 256) c += (k_[i] > cur) ? 1 : 0;
  for (int o = 32; o; o >>= 1) c += __shfl_down(c, o, 64);
  if ((t & 63) == 0) red[t >> 6] = c;
  __syncthreads();
  if (t == 0) {
    Vout[b] = cur;
    cgt[b] = red[0] + red[1] + red[2] + red[3];
  }
}

// ---------------- compact selected indices -----------------------------------
__global__ void __launch_bounds__(256) select_kernel(
    const uint32_t* __restrict__ keys, const uint32_t* __restrict__ V,
    const int* __restrict__ cgt, int* __restrict__ cnts,
    int* __restrict__ sel_idx, int* __restrict__ tok2slot) {
  int i = blockIdx.x * 256 + threadIdx.x;  // 0..16383
  int b = i >> 12, l = i & (LL - 1);
  uint32_t k = keys[i], v = V[b];
  int slot = -1;
  if (k > v) {
    slot = atomicAdd(&cnts[b], 1);
  } else if (k == v) {
    int e = atomicAdd(&cnts[NB + b], 1);
    int s = CAP - 1 - e;
    if (s >= cgt[b]) slot = s;
  }
  tok2slot[i] = slot;
  if (slot >= 0) sel_idx[b * CAP + slot] = l;
}

// ---------------- gather selected rows, f32 -> bf16 --------------------------
__global__ void __launch_bounds__(256) gather_kernel(
    const float* __restrict__ x, const int* __restrict__ sel_idx,
    ushort* __restrict__ xsel) {
  int r = blockIdx.x;  // 0..8191
  int b = r >> 11, s = r & (CAP - 1);
  int l = sel_idx[b * CAP + s];
  int t = threadIdx.x;
  const float4* src = (const float4*)(x + ((size_t)(b * LL + l)) * DD);
  float4 a0 = src[2 * t], a1 = src[2 * t + 1];
  u16x8 o;
  o[0] = f2b(a0.x); o[1] = f2b(a0.y); o[2] = f2b(a0.z); o[3] = f2b(a0.w);
  o[4] = f2b(a1.x); o[5] = f2b(a1.y); o[6] = f2b(a1.z); o[7] = f2b(a1.w);
  ((u16x8*)(xsel + (size_t)r * DD))[t] = o;
}

// ---------------- transpose f32 [R][C] -> bf16 [C][R] ------------------------
__global__ void transpose_kernel(const float* __restrict__ in,
                                 ushort* __restrict__ out, int R, int C) {
  __shared__ float tile[32][33];
  int c0 = blockIdx.x * 32, r0 = blockIdx.y * 32;
  int tx = threadIdx.x, ty = threadIdx.y;  // (32,8)
#pragma unroll
  for (int i = 0; i < 4; i++)
    tile[ty + i * 8][tx] = in[(size_t)(r0 + ty + i * 8) * C + c0 + tx];
  __syncthreads();
#pragma unroll
  for (int i = 0; i < 4; i++)
    out[(size_t)(c0 + ty + i * 8) * R + r0 + tx] = f2b(tile[tx][ty + i * 8]);
}

// ============================================================================
// 256x256 8-phase bf16 GEMM (T1+T2+T3+T4+T5).  C = act(A @ BT^T + bias)
// A [M][K] bf16 row-major, BT [N][K] bf16 row-major, C [M][N] bf16.
// 512 threads = 8 waves (2M x 4N); per-wave C tile 128x64; BK=64, dbuf LDS.
// LDS swizzle: byte ^= ((byte>>9)&1)<<5 within each 16KB [128][64] half-tile,
// applied on the pre-swizzled global source (stage) and the ds_read address.
// ============================================================================
#define MFMA_(d, a, b) d = __builtin_amdgcn_mfma_f32_16x16x32_bf16(a, b, d, 0, 0, 0)

template <int K, int N, bool GELU>
__global__ __launch_bounds__(512, 2) void gemm256_kernel(
    const ushort* __restrict__ A, const ushort* __restrict__ BT,
    const float* __restrict__ bias, ushort* __restrict__ C) {
  __shared__ char lds[131072];
  char* ldsC = (char*)lds;
  const int t = threadIdx.x;
  const int wave = t >> 6, lane = t & 63;
  const int wr = wave >> 2, wc = wave & 3;  // 2 x 4 wave grid

  // bijective XCD swizzle (nwg divisible by 8 for both instantiations)
  int gx = gridDim.x;
  int nwg = gx * gridDim.y;
  int flat = blockIdx.y * gx + blockIdx.x;
  int swzb = (flat & 7) * (nwg >> 3) + (flat >> 3);
  int bm = (swzb / gx) * 256;
  int bn = (swzb % gx) * 256;

  // ---- staging source pointers (pre-swizzled global column) ----
  const int rr = t >> 3;  // row 0..63 within half (load j=0); +64 for j=1
  const int scb = ((t & 7) << 4) ^ (((t >> 5) & 1) << 5);
  const size_t j1off = (size_t)64 * K * 2;
  const char* srcA0 = (const char*)A + ((size_t)(bm + rr) * K) * 2 + scb;
  const char* srcA1 = (const char*)A + ((size_t)(bm + 128 + rr) * K) * 2 + scb;
  const char* srcB0 = (const char*)BT + ((size_t)(bn + rr) * K) * 2 + scb;
  const char* srcB1 = (const char*)BT + ((size_t)(bn + 128 + rr) * K) * 2 + scb;

#define STAGE(srcPtr, kb, ldsOff)                                                   \
  do {                                                                              \
    __builtin_amdgcn_global_load_lds(                                               \
        (const __attribute__((address_space(1))) void*)((srcPtr) + (kb)),           \
        (__attribute__((address_space(3))) void*)(ldsC + (ldsOff) + wave * 1024),   \
        16, 0, 0);                                                                  \
    __builtin_amdgcn_global_load_lds(                                               \
        (const __attribute__((address_space(1))) void*)((srcPtr) + (kb) + j1off),   \
        (__attribute__((address_space(3))) void*)(ldsC + (ldsOff) + 8192 + wave * 1024), \
        16, 0, 0);                                                                  \
  } while (0)

  // ---- per-lane ds_read constants ----
  const int l15 = lane & 15;
  const int g = lane >> 4;
  const int swzr = ((lane >> 2) & 1) << 5;
  const int cb0 = (g << 4) ^ swzr;          // ks=0 fragment byte col
  const int cb1 = (64 | (g << 4)) ^ swzr;   // ks=1
  const int rb = l15 << 7;                  // row * 128B

  f32x4 acc[8][4];
#pragma unroll
  for (int m = 0; m < 8; m++)
#pragma unroll
    for (int n = 0; n < 4; n++) acc[m][n] = (f32x4){0.f, 0.f, 0.f, 0.f};

  bf16x8 alo[4][2], ahi[4][2], b01[2][2], b23[2][2];
  const int NT = K / 64;

  // ---- prologue: tile0 (all 4 halves) -> buf0; tile1 A halves -> buf1 ----
  STAGE(srcA0, 0, 0);
  STAGE(srcA1, 0, 16384);
  STAGE(srcB0, 0, 32768);
  STAGE(srcB1, 0, 49152);
  STAGE(srcA0, 128, 65536 + 0);
  STAGE(srcA1, 128, 65536 + 16384);
  asm volatile("s_waitcnt vmcnt(4)" ::: "memory");
  __builtin_amdgcn_sched_barrier(0);
  __builtin_amdgcn_s_barrier();

  for (int kt = 0; kt < NT; ++kt) {
    const int p = kt & 1;
    const int bufP = p << 16, bufQ = (p ^ 1) << 16;
    const char* aP = ldsC + bufP + wr * 16384 + rb;
    const char* bP = ldsC + bufP + 32768 + ((wc >> 1) * 16384) + ((wc & 1) * 8192) + rb;
    const size_t kb1 = (size_t)(kt + 1) << 7;
    const size_t kb2 = (size_t)(kt + 2) << 7;

    // ---------------- P1: read alo + b01; stage B0(t+1)->bufQ ----------------
#pragma unroll
    for (int m = 0; m < 4; m++) {
      alo[m][0] = *(const bf16x8*)(aP + (m << 11) + cb0);
      alo[m][1] = *(const bf16x8*)(aP + (m << 11) + cb1);
    }
#pragma unroll
    for (int n = 0; n < 2; n++) {
      b01[n][0] = *(const bf16x8*)(bP + (n << 11) + cb0);
      b01[n][1] = *(const bf16x8*)(bP + (n << 11) + cb1);
    }
    if (kt + 1 < NT) STAGE(srcB0, kb1, bufQ + 32768);
    __builtin_amdgcn_s_barrier();
    asm volatile("s_waitcnt lgkmcnt(0)" ::: "memory");
    __builtin_amdgcn_sched_barrier(0);
    __builtin_amdgcn_s_setprio(1);
#pragma unroll
    for (int m = 0; m < 4; m++)
#pragma unroll
      for (int n = 0; n < 2; n++) {
        MFMA_(acc[m][n], alo[m][0], b01[n][0]);
        MFMA_(acc[m][n], alo[m][1], b01[n][1]);
      }
    __builtin_amdgcn_s_setprio(0);
    __builtin_amdgcn_s_barrier();

    // ---------------- P2: read ahi; stage B1(t+1)->bufQ ----------------------
#pragma unroll
    for (int m = 0; m < 4; m++) {
      ahi[m][0] = *(const bf16x8*)(aP + ((m + 4) << 11) + cb0);
      ahi[m][1] = *(const bf16x8*)(aP + ((m + 4) << 11) + cb1);
    }
    if (kt + 1 < NT) STAGE(srcB1, kb1, bufQ + 49152);
    __builtin_amdgcn_s_barrier();
    asm volatile("s_waitcnt lgkmcnt(0)" ::: "memory");
    __builtin_amdgcn_sched_barrier(0);
    __builtin_amdgcn_s_setprio(1);
#pragma unroll
    for (int m = 0; m < 4; m++)
#pragma unroll
      for (int n = 0; n < 2; n++) {
        MFMA_(acc[m + 4][n], ahi[m][0], b01[n][0]);
        MFMA_(acc[m + 4][n], ahi[m][1], b01[n][1]);
      }
    __builtin_amdgcn_s_setprio(0);
    __builtin_amdgcn_s_barrier();

    // ---------------- P3: read b23; stage A0(t+2)->bufP ----------------------
    // (all bufP reads were issued by end of P2 and drained by each wave's
    //  lgkmcnt(0); the P2 tail barrier makes that true block-wide, so staging
    //  tile t+2's A halves into bufP is race-free from here on.)
#pragma unroll
    for (int n = 0; n < 2; n++) {
      b23[n][0] = *(const bf16x8*)(bP + ((n + 2) << 11) + cb0);
      b23[n][1] = *(const bf16x8*)(bP + ((n + 2) << 11) + cb1);
    }
    if (kt + 2 < NT) STAGE(srcA0, kb2, bufP + 0);
    __builtin_amdgcn_s_barrier();
    asm volatile("s_waitcnt lgkmcnt(0)" ::: "memory");
    __builtin_amdgcn_sched_barrier(0);
    __builtin_amdgcn_s_setprio(1);
#pragma unroll
    for (int m = 0; m < 4; m++)
#pragma unroll
      for (int n = 0; n < 2; n++) {
        MFMA_(acc[m + 4][n + 2], ahi[m][0], b23[n][0]);
        MFMA_(acc[m + 4][n + 2], ahi[m][1], b23[n][1]);
      }
    __builtin_amdgcn_s_setprio(0);
    __builtin_amdgcn_s_barrier();

    // ---------------- P4: stage A1(t+2)->bufP; counted vmcnt -----------------
    if (kt + 2 < NT) STAGE(srcA1, kb2, bufP + 16384);
    __builtin_amdgcn_s_barrier();
    __builtin_amdgcn_s_setprio(1);
#pragma unroll
    for (int m = 0; m < 4; m++)
#pragma unroll
      for (int n = 0; n < 2; n++) {
        MFMA_(acc[m][n + 2], alo[m][0], b23[n][0]);
        MFMA_(acc[m][n + 2], alo[m][1], b23[n][1]);
      }
    __builtin_amdgcn_s_setprio(0);
    if (kt + 1 < NT) {
      if (kt + 2 < NT) {
        asm volatile("s_waitcnt vmcnt(4)" ::: "memory");  // tile t+1 landed; P3/P4 stages in flight
      } else {
        asm volatile("s_waitcnt vmcnt(0)" ::: "memory");  // tail: drain
      }
      __builtin_amdgcn_sched_barrier(0);
    }
    __builtin_amdgcn_s_barrier();
  }

  // ---- epilogue: bias (+gelu) -> bf16 store ----
  const int colBase = bn + wc * 64 + l15;
  const int rowBase = bm + wr * 128 + (g << 2);
  float bs[4];
#pragma unroll
  for (int n = 0; n < 4; n++) bs[n] = bias[colBase + n * 16];
#pragma unroll
  for (int m = 0; m < 8; m++)
#pragma unroll
    for (int n = 0; n < 4; n++) {
      int col = colBase + n * 16;
#pragma unroll
      for (int r = 0; r < 4; r++) {
        int row = rowBase + m * 16 + r;
        float v = acc[m][n][r] + bs[n];
        if (GELU) {
          float u = 1.5957691216057308f * (v + 0.044715f * v * v * v);
          v = v / (1.f + __expf(-u));
        }
        C[(size_t)row * N + col] = f2b(v);
      }
    }
#undef STAGE
}

// ---------------- final: out = x (unselected) | blend (selected) -------------
__global__ void __launch_bounds__(256) final_kernel(
    const float* __restrict__ x, const float* __restrict__ probs,
    const int* __restrict__ tok2slot, const ushort* __restrict__ out_sel,
    float* __restrict__ outF) {
  int tok = blockIdx.x;
  int b = tok >> 12;
  int slot = tok2slot[tok];
  float p = probs[tok];
  int t = threadIdx.x;
  const float4* xr = (const float4*)(x + (size_t)tok * DD);
  float4* od = (float4*)(outF + (size_t)tok * DD);
  float4 a0 = xr[2 * t], a1 = xr[2 * t + 1];
  if (slot >= 0) {
    u16x8 q = ((const u16x8*)(out_sel + ((size_t)((b << 11) + slot)) * DD))[t];
    float q1p = 1.f - p;
    a0.x = p * b2f(q[0]) + q1p * a0.x;
    a0.y = p * b2f(q[1]) + q1p * a0.y;
    a0.z = p * b2f(q[2]) + q1p * a0.z;
    a0.w = p * b2f(q[3]) + q1p * a0.w;
    a1.x = p * b2f(q[4]) + q1p * a1.x;
    a1.y = p * b2f(q[5]) + q1p * a1.y;
    a1.z = p * b2f(q[6]) + q1p * a1.z;
    a1.w = p * b2f(q[7]) + q1p * a1.w;
  }
  od[2 * t] = a0;
  od[2 * t + 1] = a1;
}

// ---------------- aux loss ---------------------------------------------------
__global__ void aux_kernel(const float* __restrict__ probsum,
                           float* __restrict__ outaux) {
  if (threadIdx.x == 0) {
    float s = 0.f;
#pragma unroll
    for (int b = 0; b < NB; b++) {
      float m = probsum[b] * (1.f / (float)LL) - 0.5f;
      s += m * m;
    }
    outaux[0] = 0.01f * s * (1.f / (float)NB);
  }
}

// ---------------- launch -----------------------------------------------------
extern "C" void kernel_launch(void* const* d_in, const int* in_sizes, int n_in,
                              void* d_out, int out_size, void* d_ws,
                              size_t ws_size, hipStream_t stream) {
  const float* x = (const float*)d_in[0];
  const float* w_router = (const float*)d_in[1];
  const float* W1 = (const float*)d_in[2];  // [D][H]
  const float* b1 = (const float*)d_in[3];
  const float* W2 = (const float*)d_in[4];  // [H][D]
  const float* b2 = (const float*)d_in[5];
  float* outF = (float*)d_out;

  char* w = (char*)d_ws;
  uint32_t* keys    = (uint32_t*)(w);                // 64 KB
  float*    probs   = (float*)(w + 65536);           // 64 KB
  float*    probsum = (float*)(w + 131072);          // 256 B
  int*      cnts    = (int*)(w + 131328);            // 256 B
  uint32_t* V       = (uint32_t*)(w + 131584);       // 256 B
  int*      cgt     = (int*)(w + 131840);            // 256 B
  int*      sel_idx = (int*)(w + 132096);            // 32 KB
  int*      tok2slot= (int*)(w + 164864);            // 64 KB
  ushort*   xsel    = (ushort*)(w + 230400);                        // [8192][2048]
  ushort*   W1T     = (ushort*)(w + 230400 + 33554432);             // [H][D]
  ushort*   W2T     = (ushort*)(w + 230400 + 2 * 33554432);         // [D][H]
  ushort*   out_sel = (ushort*)(w + 230400 + (size_t)3 * 33554432); // [8192][2048]

  ushort* hbuf = (ushort*)d_out;  // h [8192][8192] bf16 scratch, overwritten later

  init_kernel<<<1, 64, 0, stream>>>(probsum, cnts);
  router_kernel<<<NB * LL, 256, 0, stream>>>(x, w_router, keys, probs, probsum);
  thresh_kernel<<<NB, 256, 0, stream>>>(keys, V, cgt);
  select_kernel<<<NB * LL / 256, 256, 0, stream>>>(keys, V, cgt, cnts, sel_idx,
                                                   tok2slot);
  gather_kernel<<<NB * CAP, 256, 0, stream>>>(x, sel_idx, xsel);
  transpose_kernel<<<dim3(HH / 32, DD / 32), dim3(32, 8), 0, stream>>>(W1, W1T,
                                                                       DD, HH);
  transpose_kernel<<<dim3(DD / 32, HH / 32), dim3(32, 8), 0, stream>>>(W2, W2T,
                                                                       HH, DD);
  gemm256_kernel<DD, HH, true>
      <<<dim3(HH / 256, (NB * CAP) / 256), 512, 0, stream>>>(xsel, W1T, b1, hbuf);
  gemm256_kernel<HH, DD, false>
      <<<dim3(DD / 256, (NB * CAP) / 256), 512, 0, stream>>>(hbuf, W2T, b2, out_sel);
  final_kernel<<<NB * LL, 256, 0, stream>>>(x, probs, tok2slot, out_sel, outF);
  aux_kernel<<<1, 64, 0, stream>>>(probsum, outF + BLD);
}